// Round 7
// baseline (94.079 us; speedup 1.0000x reference)
//
#include <hip/hip_runtime.h>
#include <math.h>

// EdgeWeightLearner, 2-kernel pipeline (dispatch-count-minimized):
//   K1 (fused, independent phases):
//     (a) p_row[n] = dot(x[n], w[0:64]); p_col[n] = dot(x[n], w[64:128])
//     (b) packed[e] = row[e] | col[e]<<16   (node ids < 50000 < 2^16)
//   K2: f = fri[e]; unpack (r1,c1)=packed[e], (r2,c2)=packed[f]
//       out[e] = sigmoid(p_row[r1]+p_col[c1]) * sigmoid(p_row[r2]+p_col[c2])
// Round-4 lesson: the random-gather working set must fit the 4 MiB per-XCD
// L2. Packing indices shrinks it from 6.8 MB (row+col) to 3.2 MB (packed),
// and the sequential packed[e] stream constructively warms L2 for the
// packed[f] gathers. fri load / out store are nontemporal (no reuse).

#define IN_CH 64

typedef int   ntint4  __attribute__((ext_vector_type(4)));
typedef float ntfloat4 __attribute__((ext_vector_type(4)));

__device__ __forceinline__ float fast_sigmoid(float x) {
    return 1.0f / (1.0f + __expf(-x));
}

// K1: threads 0..16*n_nodes-1 do node dots (16 lanes/node, float4 each);
//     threads 0..n_edges/4-1 also pack 4 edges each (independent work).
__global__ __launch_bounds__(256)
void prep_kernel(const float* __restrict__ x,
                 const float* __restrict__ w_lin,
                 const int* __restrict__ row,
                 const int* __restrict__ col,
                 float* __restrict__ p_row,
                 float* __restrict__ p_col,
                 unsigned int* __restrict__ packed,
                 int n_nodes, int n_edges) {
    int tid = blockIdx.x * blockDim.x + threadIdx.x;

    // (a) node dot products
    int node = tid >> 4;
    int sub  = tid & 15;
    if (node < n_nodes) {
        const float4 xv = *reinterpret_cast<const float4*>(x + node * IN_CH + sub * 4);
        const float4 wr = *reinterpret_cast<const float4*>(w_lin + sub * 4);
        const float4 wc = *reinterpret_cast<const float4*>(w_lin + IN_CH + sub * 4);
        float pr = xv.x * wr.x + xv.y * wr.y + xv.z * wr.z + xv.w * wr.w;
        float pc = xv.x * wc.x + xv.y * wc.y + xv.z * wc.z + xv.w * wc.w;
        #pragma unroll
        for (int m = 1; m < 16; m <<= 1) {
            pr += __shfl_xor(pr, m, 64);
            pc += __shfl_xor(pc, m, 64);
        }
        if (sub == 0) { p_row[node] = pr; p_col[node] = pc; }
    }

    // (b) pack 4 edges per thread (coalesced int4 reads, uint4 write)
    int e0 = tid * 4;
    if (e0 + 3 < n_edges) {
        int4 r = *reinterpret_cast<const int4*>(row + e0);
        int4 c = *reinterpret_cast<const int4*>(col + e0);
        uint4 pk;
        pk.x = (unsigned int)r.x | ((unsigned int)c.x << 16);
        pk.y = (unsigned int)r.y | ((unsigned int)c.y << 16);
        pk.z = (unsigned int)r.z | ((unsigned int)c.z << 16);
        pk.w = (unsigned int)r.w | ((unsigned int)c.w << 16);
        *reinterpret_cast<uint4*>(packed + e0) = pk;
    } else if (e0 < n_edges) {
        for (int e = e0; e < n_edges; ++e)
            packed[e] = (unsigned int)row[e] | ((unsigned int)col[e] << 16);
    }
}

// K2: 8 edges/thread. Streams packed (warms L2) + fri (nt), one 4B random
// gather from the 3.2 MB packed array (L2-fit), 4 p-gathers (400 KB tables),
// 2 sigmoids, nt f32 store.
__global__ __launch_bounds__(256)
void edge_out_kernel(const unsigned int* __restrict__ packed,
                     const int* __restrict__ fri,
                     const float* __restrict__ p_row,
                     const float* __restrict__ p_col,
                     float* __restrict__ out,
                     int n_edges) {
    int e0 = (blockIdx.x * blockDim.x + threadIdx.x) * 8;
    if (e0 + 7 < n_edges) {
        uint4 pk0 = *reinterpret_cast<const uint4*>(packed + e0);
        uint4 pk1 = *reinterpret_cast<const uint4*>(packed + e0 + 4);
        ntint4 f0 = __builtin_nontemporal_load(reinterpret_cast<const ntint4*>(fri + e0));
        ntint4 f1 = __builtin_nontemporal_load(reinterpret_cast<const ntint4*>(fri + e0 + 4));
        // random 4B gathers (issue all 8 early; independent chains)
        unsigned int g0 = packed[f0.x];
        unsigned int g1 = packed[f0.y];
        unsigned int g2 = packed[f0.z];
        unsigned int g3 = packed[f0.w];
        unsigned int g4 = packed[f1.x];
        unsigned int g5 = packed[f1.y];
        unsigned int g6 = packed[f1.z];
        unsigned int g7 = packed[f1.w];

        ntfloat4 o0, o1;
        o0.x = fast_sigmoid(p_row[pk0.x & 0xFFFF] + p_col[pk0.x >> 16])
             * fast_sigmoid(p_row[g0 & 0xFFFF]    + p_col[g0 >> 16]);
        o0.y = fast_sigmoid(p_row[pk0.y & 0xFFFF] + p_col[pk0.y >> 16])
             * fast_sigmoid(p_row[g1 & 0xFFFF]    + p_col[g1 >> 16]);
        o0.z = fast_sigmoid(p_row[pk0.z & 0xFFFF] + p_col[pk0.z >> 16])
             * fast_sigmoid(p_row[g2 & 0xFFFF]    + p_col[g2 >> 16]);
        o0.w = fast_sigmoid(p_row[pk0.w & 0xFFFF] + p_col[pk0.w >> 16])
             * fast_sigmoid(p_row[g3 & 0xFFFF]    + p_col[g3 >> 16]);
        o1.x = fast_sigmoid(p_row[pk1.x & 0xFFFF] + p_col[pk1.x >> 16])
             * fast_sigmoid(p_row[g4 & 0xFFFF]    + p_col[g4 >> 16]);
        o1.y = fast_sigmoid(p_row[pk1.y & 0xFFFF] + p_col[pk1.y >> 16])
             * fast_sigmoid(p_row[g5 & 0xFFFF]    + p_col[g5 >> 16]);
        o1.z = fast_sigmoid(p_row[pk1.z & 0xFFFF] + p_col[pk1.z >> 16])
             * fast_sigmoid(p_row[g6 & 0xFFFF]    + p_col[g6 >> 16]);
        o1.w = fast_sigmoid(p_row[pk1.w & 0xFFFF] + p_col[pk1.w >> 16])
             * fast_sigmoid(p_row[g7 & 0xFFFF]    + p_col[g7 >> 16]);
        __builtin_nontemporal_store(o0, reinterpret_cast<ntfloat4*>(out + e0));
        __builtin_nontemporal_store(o1, reinterpret_cast<ntfloat4*>(out + e0 + 4));
    } else {
        for (int e = e0; e < n_edges; ++e) {
            unsigned int pk = packed[e];
            unsigned int g  = packed[fri[e]];
            out[e] = fast_sigmoid(p_row[pk & 0xFFFF] + p_col[pk >> 16])
                   * fast_sigmoid(p_row[g & 0xFFFF]  + p_col[g >> 16]);
        }
    }
}

extern "C" void kernel_launch(void* const* d_in, const int* in_sizes, int n_in,
                              void* d_out, int out_size, void* d_ws, size_t ws_size,
                              hipStream_t stream) {
    const float* x     = (const float*)d_in[0];   // (N_NODES, 64) f32
    const float* w_lin = (const float*)d_in[1];   // (128,) f32
    const int*   eidx  = (const int*)d_in[2];     // (2, N_EDGES) int32
    const int*   fri   = (const int*)d_in[3];     // (N_EDGES,) int32

    const int n_nodes = in_sizes[0] / IN_CH;
    const int n_edges = in_sizes[3];

    const int* row = eidx;
    const int* col = eidx + n_edges;

    float*        p_row  = (float*)d_ws;               // n_nodes f32 (200 KB)
    float*        p_col  = p_row + n_nodes;            // n_nodes f32 (200 KB)
    unsigned int* packed = (unsigned int*)(p_col + n_nodes);  // n_edges u32 (3.2 MB)
    float*        out    = (float*)d_out;

    // K1: grid covers max(node work = 16*n_nodes, pack work = n_edges/4)
    {
        long long node_threads = (long long)n_nodes * 16;
        long long pack_threads = (n_edges + 3) / 4;
        long long threads = node_threads > pack_threads ? node_threads : pack_threads;
        int block = 256;
        int grid = (int)((threads + block - 1) / block);
        prep_kernel<<<grid, block, 0, stream>>>(x, w_lin, row, col,
                                                p_row, p_col, packed,
                                                n_nodes, n_edges);
    }
    // K2: 8 edges per thread
    {
        int block = 256;
        int grid = (n_edges / 8 + block - 1) / block;
        edge_out_kernel<<<grid, block, 0, stream>>>(packed, fri, p_row, p_col,
                                                    out, n_edges);
    }
}

// Round 9
// 88.225 us; speedup vs baseline: 1.0664x; 1.0664x over previous
//
#include <hip/hip_runtime.h>
#include <hip/hip_fp16.h>
#include <math.h>

// EdgeWeightLearner, 3-kernel pipeline (store-then-gather; fp16 weights).
// Proven-best structure (R6 = 87.75 us): 3 random gathers/edge total.
//   K1: p_row[n] = dot(x[n], w[0:64]);  p_col[n] = dot(x[n], w[64:128])
//   K2: wh[e] = (half) sigmoid(p_row[row[e]] + p_col[col[e]])   (2 gathers)
//   K3: out[e] = (float)wh[e] * (float)wh[fri[e]]               (1 gather)
// R4/R7 lesson: recompute-fusion multiplies gather count and always loses;
// gather issue (64 L1 cycles per divergent wave64 gather) is the cost, not
// HBM bytes. R8 delta: 4 edges/thread (200k threads, 2x waves vs R6) for
// better gather-latency hiding.

#define IN_CH 64

// K1: 16 lanes per node, float4 each -> 64 ch. Perfectly coalesced.
__global__ void node_dots_kernel(const float* __restrict__ x,
                                 const float* __restrict__ w_lin,
                                 float* __restrict__ p_row,
                                 float* __restrict__ p_col,
                                 int n_nodes) {
    int tid = blockIdx.x * blockDim.x + threadIdx.x;
    int node = tid >> 4;
    int sub  = tid & 15;
    if (node >= n_nodes) return;
    const float4 xv = *reinterpret_cast<const float4*>(x + node * IN_CH + sub * 4);
    const float4 wr = *reinterpret_cast<const float4*>(w_lin + sub * 4);
    const float4 wc = *reinterpret_cast<const float4*>(w_lin + IN_CH + sub * 4);
    float pr = xv.x * wr.x + xv.y * wr.y + xv.z * wr.z + xv.w * wr.w;
    float pc = xv.x * wc.x + xv.y * wc.y + xv.z * wc.z + xv.w * wc.w;
    #pragma unroll
    for (int m = 1; m < 16; m <<= 1) {
        pr += __shfl_xor(pr, m, 64);
        pc += __shfl_xor(pc, m, 64);
    }
    if (sub == 0) {
        p_row[node] = pr;
        p_col[node] = pc;
    }
}

__device__ __forceinline__ float fast_sigmoid(float x) {
    return 1.0f / (1.0f + __expf(-x));
}

// K2: 4 edges/thread; coalesced int4 index loads, 8 random p-gathers
// (2x 200 KB tables, L1/L2-resident), fp16x4 store.
__global__ __launch_bounds__(256)
void edge_sigmoid_kernel(const int* __restrict__ row,
                         const int* __restrict__ col,
                         const float* __restrict__ p_row,
                         const float* __restrict__ p_col,
                         __half* __restrict__ wh,
                         int n_edges) {
    int e0 = (blockIdx.x * blockDim.x + threadIdx.x) * 4;
    if (e0 + 3 < n_edges) {
        int4 r = *reinterpret_cast<const int4*>(row + e0);
        int4 c = *reinterpret_cast<const int4*>(col + e0);
        float l0 = p_row[r.x] + p_col[c.x];
        float l1 = p_row[r.y] + p_col[c.y];
        float l2 = p_row[r.z] + p_col[c.z];
        float l3 = p_row[r.w] + p_col[c.w];
        __half2 h0 = __floats2half2_rn(fast_sigmoid(l0), fast_sigmoid(l1));
        __half2 h1 = __floats2half2_rn(fast_sigmoid(l2), fast_sigmoid(l3));
        __half2* dst = reinterpret_cast<__half2*>(wh + e0);
        dst[0] = h0; dst[1] = h1;
    } else {
        for (int e = e0; e < n_edges; ++e)
            wh[e] = __float2half(fast_sigmoid(p_row[row[e]] + p_col[col[e]]));
    }
}

// K3: 4 edges/thread; stream wh + fri, 4 independent random fp16 gathers
// into a 1.6 MB array (L2-resident), f32x4 store.
__global__ __launch_bounds__(256)
void edge_pair_kernel(const __half* __restrict__ wh,
                      const int* __restrict__ fri,
                      float* __restrict__ out,
                      int n_edges) {
    int e0 = (blockIdx.x * blockDim.x + threadIdx.x) * 4;
    if (e0 + 3 < n_edges) {
        const __half2* wp = reinterpret_cast<const __half2*>(wh + e0);
        __half2 w0 = wp[0], w1 = wp[1];
        int4 i = *reinterpret_cast<const int4*>(fri + e0);
        float g0 = __half2float(wh[i.x]);
        float g1 = __half2float(wh[i.y]);
        float g2 = __half2float(wh[i.z]);
        float g3 = __half2float(wh[i.w]);
        float4 o;
        o.x = __half2float(w0.x) * g0;
        o.y = __half2float(w0.y) * g1;
        o.z = __half2float(w1.x) * g2;
        o.w = __half2float(w1.y) * g3;
        *reinterpret_cast<float4*>(out + e0) = o;
    } else {
        for (int e = e0; e < n_edges; ++e)
            out[e] = __half2float(wh[e]) * __half2float(wh[fri[e]]);
    }
}

extern "C" void kernel_launch(void* const* d_in, const int* in_sizes, int n_in,
                              void* d_out, int out_size, void* d_ws, size_t ws_size,
                              hipStream_t stream) {
    const float* x     = (const float*)d_in[0];   // (N_NODES, 64) f32
    const float* w_lin = (const float*)d_in[1];   // (128,) f32
    const int*   eidx  = (const int*)d_in[2];     // (2, N_EDGES) int32
    const int*   fri   = (const int*)d_in[3];     // (N_EDGES,) int32

    const int n_nodes = in_sizes[0] / IN_CH;
    const int n_edges = in_sizes[3];

    const int* row = eidx;
    const int* col = eidx + n_edges;

    float*  p_row = (float*)d_ws;                 // n_nodes f32
    float*  p_col = p_row + n_nodes;              // n_nodes f32
    __half* wh    = (__half*)(p_col + n_nodes);   // n_edges fp16 (1.6 MB)
    float*  out   = (float*)d_out;                // n_edges f32

    // K1: 16 threads per node
    {
        long long threads = (long long)n_nodes * 16;
        int block = 256;
        int grid = (int)((threads + block - 1) / block);
        node_dots_kernel<<<grid, block, 0, stream>>>(x, w_lin, p_row, p_col, n_nodes);
    }
    // K2: 4 edges per thread
    {
        int block = 256;
        int grid = (n_edges / 4 + block - 1) / block;
        edge_sigmoid_kernel<<<grid, block, 0, stream>>>(row, col, p_row, p_col, wh, n_edges);
    }
    // K3: 4 edges per thread
    {
        int block = 256;
        int grid = (n_edges / 4 + block - 1) / block;
        edge_pair_kernel<<<grid, block, 0, stream>>>(wh, fri, out, n_edges);
    }
}